// Round 10
// baseline (213.923 us; speedup 1.0000x reference)
//
#include <hip/hip_runtime.h>
#include <hip/hip_bf16.h>
#include <math.h>

#define NH 16
#define T_ 2048
#define B_ 2
#define D_ 1024
#define EPS 1e-6f

typedef __attribute__((ext_vector_type(8))) short bf16x8;
typedef __attribute__((ext_vector_type(4))) float f32x4;

__device__ __forceinline__ float wred_sum(float v){
  #pragma unroll
  for (int o = 32; o > 0; o >>= 1) v += __shfl_xor(v, o, 64);
  return v;
}

__device__ __forceinline__ unsigned pack_bf16(float a, float b){
  __hip_bfloat162 t = __float22bfloat162_rn(make_float2(a, b));
  unsigned r; __builtin_memcpy(&r, &t, 4); return r;
}

__device__ __forceinline__ void gload_lds16(const void* g, void* l){
  __builtin_amdgcn_global_load_lds((const __attribute__((address_space(1))) void*)g,
                                   (__attribute__((address_space(3))) void*)l, 16, 0, 0);
}

// ---- convert x + weights to bf16; Wkvb rows PERMUTED: [h*48+d | 768+h*64+dv] ----
__global__ __launch_bounds__(256)
void cvt5(const float* __restrict__ x, const float* __restrict__ wq,
          const float* __restrict__ wkva, const float* __restrict__ wkvb,
          const float* __restrict__ wo,
          __hip_bfloat16* __restrict__ xb, __hip_bfloat16* __restrict__ wqb,
          __hip_bfloat16* __restrict__ wkvab, __hip_bfloat16* __restrict__ wkvbb,
          __hip_bfloat16* __restrict__ wob)
{
  const int i = blockIdx.x * 256 + threadIdx.x;     // float4 index, 1,667,072 total
  const float* s; __hip_bfloat16* d; size_t soff, doff;
  if      (i < 1048576) { s = x;    d = xb;    soff = doff = i; }
  else if (i < 1310720) { s = wq;   d = wqb;   soff = doff = i - 1048576; }
  else if (i < 1347584) { s = wkva; d = wkvab; soff = doff = i - 1310720; }
  else if (i < 1404928) {
    const int off = i - 1347584;                    // float4 idx into 1792x128
    const int srow = off >> 5, c4 = off & 31;
    const int h = srow / 112, dd = srow % 112;
    const int drow = (dd < 48) ? (h*48 + dd) : (768 + h*64 + (dd - 48));
    s = wkvb; d = wkvbb; soff = off; doff = (size_t)drow*32 + c4;
  }
  else                  { s = wo;   d = wob;   soff = doff = i - 1404928; }
  float4 v = *(const float4*)(s + soff * 4);
  *(__hip_bfloat162*)(d + doff * 4)     = __float22bfloat162_rn(make_float2(v.x, v.y));
  *(__hip_bfloat162*)(d + doff * 4 + 2) = __float22bfloat162_rn(make_float2(v.z, v.w));
}

// ---- bf16 MFMA GEMM, 128x64 tile, DOUBLE-BUFFERED staging (48KB LDS) ----
template<typename CT>
__global__ __launch_bounds__(256, 2)
void gemm_bt64(const __hip_bfloat16* __restrict__ A, const __hip_bfloat16* __restrict__ W,
               CT* __restrict__ C, int M, int N, int K)
{
  __shared__ __hip_bfloat16 As[2][128 * 64];   // 32 KB
  __shared__ __hip_bfloat16 Ws[2][64 * 64];    // 16 KB
  const int tid = threadIdx.x;
  const int wv = tid >> 6, lane = tid & 63;
  const int m = lane & 15, quad = lane >> 4;
  const int bm = blockIdx.y * 128, bn = blockIdx.x * 64;

  const __hip_bfloat16* ga[4];
  const __hip_bfloat16* gw[2];
  #pragma unroll
  for (int i = 0; i < 4; i++) {
    const int slot = i*256 + tid;
    const int row = slot >> 3, cb = slot & 7;
    ga[i] = A + (size_t)(bm + row) * K + ((cb ^ (row & 7)) << 3);
  }
  #pragma unroll
  for (int i = 0; i < 2; i++) {
    const int slot = i*256 + tid;
    const int row = slot >> 3, cb = slot & 7;
    int wr = bn + row; if (wr >= N) wr = N - 1;
    gw[i] = W + (size_t)wr * K + ((cb ^ (row & 7)) << 3);
  }
  auto stage = [&](int buf){
    #pragma unroll
    for (int i = 0; i < 4; i++) { gload_lds16(ga[i], &As[buf][(i*256 + wv*64)*8]); ga[i] += 64; }
    #pragma unroll
    for (int i = 0; i < 2; i++) { gload_lds16(gw[i], &Ws[buf][(i*256 + wv*64)*8]); gw[i] += 64; }
  };

  f32x4 acc[2][4];
  #pragma unroll
  for (int mi = 0; mi < 2; mi++)
    #pragma unroll
    for (int nj = 0; nj < 4; nj++) acc[mi][nj] = (f32x4){0.f,0.f,0.f,0.f};

  stage(0);
  const int iters = K >> 6;
  for (int it = 0; it < iters; it++) {
    const int cur = it & 1;
    __syncthreads();
    if (it + 1 < iters) stage(cur ^ 1);
    #pragma unroll
    for (int ks = 0; ks < 2; ks++) {
      const int cb = ((ks*4 + quad) ^ (m & 7)) << 3;
      bf16x8 af[2], wf[4];
      #pragma unroll
      for (int mi = 0; mi < 2; mi++)
        af[mi] = *(const bf16x8*)(&As[cur][(wv*32 + mi*16 + m) * 64 + cb]);
      #pragma unroll
      for (int nj = 0; nj < 4; nj++)
        wf[nj] = *(const bf16x8*)(&Ws[cur][(nj*16 + m) * 64 + cb]);
      #pragma unroll
      for (int mi = 0; mi < 2; mi++)
        #pragma unroll
        for (int nj = 0; nj < 4; nj++)
          acc[mi][nj] = __builtin_amdgcn_mfma_f32_16x16x32_bf16(af[mi], wf[nj], acc[mi][nj], 0, 0, 0);
    }
  }

  #pragma unroll
  for (int mi = 0; mi < 2; mi++)
    #pragma unroll
    for (int nj = 0; nj < 4; nj++) {
      const int col = bn + nj*16 + m;
      if (col < N) {
        #pragma unroll
        for (int r = 0; r < 4; r++) {
          const int row = bm + wv*32 + mi*16 + quad*4 + r;
          if constexpr (sizeof(CT) == 2)
            C[(size_t)row * N + col] = (CT)__float2bfloat16(acc[mi][nj][r]);
          else
            C[(size_t)row * N + col] = acc[mi][nj][r];
        }
      }
    }
}

// ---- merged Wq(+fused RMSNorm/RoPE) and Wkva GEMM: one launch, K=1024 ----
__global__ __launch_bounds__(256, 2)
void gemm_qkva(const __hip_bfloat16* __restrict__ A, const __hip_bfloat16* __restrict__ Wqb,
               const __hip_bfloat16* __restrict__ Wkvab,
               const float* __restrict__ qw, const float* __restrict__ cosp,
               const float* __restrict__ sinp,
               __hip_bfloat16* __restrict__ qb, float* __restrict__ kva)
{
  __shared__ __hip_bfloat16 As[2][128 * 64];
  __shared__ __hip_bfloat16 Ws[2][64 * 64];
  const int K = 1024;
  const int tid = threadIdx.x;
  const int wv = tid >> 6, lane = tid & 63;
  const int m = lane & 15, quad = lane >> 4;
  const int bm = blockIdx.y * 128;
  const bool isq = blockIdx.x < 16;
  const __hip_bfloat16* W = isq ? Wqb : Wkvab;
  const int bn = isq ? blockIdx.x*64 : (blockIdx.x - 16)*64;
  const int Nw = isq ? 1024 : 144;

  const __hip_bfloat16* ga[4];
  const __hip_bfloat16* gw[2];
  #pragma unroll
  for (int i = 0; i < 4; i++) {
    const int slot = i*256 + tid;
    const int row = slot >> 3, cb = slot & 7;
    ga[i] = A + (size_t)(bm + row) * K + ((cb ^ (row & 7)) << 3);
  }
  #pragma unroll
  for (int i = 0; i < 2; i++) {
    const int slot = i*256 + tid;
    const int row = slot >> 3, cb = slot & 7;
    int wr = bn + row; if (wr >= Nw) wr = Nw - 1;
    gw[i] = W + (size_t)wr * K + ((cb ^ (row & 7)) << 3);
  }
  auto stage = [&](int buf){
    #pragma unroll
    for (int i = 0; i < 4; i++) { gload_lds16(ga[i], &As[buf][(i*256 + wv*64)*8]); ga[i] += 64; }
    #pragma unroll
    for (int i = 0; i < 2; i++) { gload_lds16(gw[i], &Ws[buf][(i*256 + wv*64)*8]); gw[i] += 64; }
  };

  f32x4 acc[2][4];
  #pragma unroll
  for (int mi = 0; mi < 2; mi++)
    #pragma unroll
    for (int nj = 0; nj < 4; nj++) acc[mi][nj] = (f32x4){0.f,0.f,0.f,0.f};

  stage(0);
  for (int it = 0; it < 16; it++) {
    const int cur = it & 1;
    __syncthreads();
    if (it < 15) stage(cur ^ 1);
    #pragma unroll
    for (int ks = 0; ks < 2; ks++) {
      const int cb = ((ks*4 + quad) ^ (m & 7)) << 3;
      bf16x8 af[2], wf[4];
      #pragma unroll
      for (int mi = 0; mi < 2; mi++)
        af[mi] = *(const bf16x8*)(&As[cur][(wv*32 + mi*16 + m) * 64 + cb]);
      #pragma unroll
      for (int nj = 0; nj < 4; nj++)
        wf[nj] = *(const bf16x8*)(&Ws[cur][(nj*16 + m) * 64 + cb]);
      #pragma unroll
      for (int mi = 0; mi < 2; mi++)
        #pragma unroll
        for (int nj = 0; nj < 4; nj++)
          acc[mi][nj] = __builtin_amdgcn_mfma_f32_16x16x32_bf16(af[mi], wf[nj], acc[mi][nj], 0, 0, 0);
    }
  }

  if (isq) {
    const int head = blockIdx.x;
    float qwv[4];
    #pragma unroll
    for (int nj = 0; nj < 4; nj++) qwv[nj] = qw[nj*16 + m];
    const int j = m & 7;
    #pragma unroll
    for (int mi = 0; mi < 2; mi++) {
      #pragma unroll
      for (int r = 0; r < 4; r++) {
        float ss = 0.f;
        #pragma unroll
        for (int nj = 0; nj < 4; nj++) { const float t = acc[mi][nj][r]; ss = fmaf(t, t, ss); }
        ss += __shfl_xor(ss, 1, 64); ss += __shfl_xor(ss, 2, 64);
        ss += __shfl_xor(ss, 4, 64); ss += __shfl_xor(ss, 8, 64);
        const float nrm = rsqrtf(ss * (1.0f/64.0f) + EPS);
        float v[4];
        #pragma unroll
        for (int nj = 0; nj < 4; nj++) v[nj] = acc[mi][nj][r] * nrm * qwv[nj];
        const int grow = bm + wv*32 + mi*16 + quad*4 + r;
        const int t = grow & (T_ - 1);
        const int b = grow >> 11;
        const float part = __shfl_xor(v[3], 8, 64);
        const float c = cosp[t*8 + j], sn = sinp[t*8 + j];
        v[3] = (m < 8) ? (v[3]*c - part*sn) : (v[3]*c + part*sn);
        __hip_bfloat16* dst = qb + ((size_t)(b*NH + head)*T_ + t)*64 + m;
        #pragma unroll
        for (int nj = 0; nj < 4; nj++) dst[nj*16] = __float2bfloat16(v[nj] * 0.125f);
      }
    }
  } else {
    #pragma unroll
    for (int mi = 0; mi < 2; mi++)
      #pragma unroll
      for (int nj = 0; nj < 4; nj++) {
        const int col = bn + nj*16 + m;
        if (col < 144) {
          #pragma unroll
          for (int r = 0; r < 4; r++) {
            const int row = bm + wv*32 + mi*16 + quad*4 + r;
            kva[(size_t)row * 144 + col] = acc[mi][nj][r];
          }
        }
      }
  }
}

// Per (b,t): RMSNorm over kv_a[:128] -> kvl16; RoPE on kv_a[128:144] -> krope16.
__global__ void prep_kv(const float* __restrict__ kva, const float* __restrict__ kw,
                        const float* __restrict__ cosp, const float* __restrict__ sinp,
                        __hip_bfloat16* __restrict__ kvl16, __hip_bfloat16* __restrict__ krope16)
{
  const int tid = threadIdx.x;   // 0..127
  const int bt = blockIdx.x;
  const int t = bt % T_;
  const float* row = kva + (size_t)bt * 144;
  const float v = row[tid];
  float s = wred_sum(v * v);
  __shared__ float red[2];
  if ((tid & 63) == 0) red[tid >> 6] = s;
  __syncthreads();
  const float total = red[0] + red[1];
  const float norm = rsqrtf(total * (1.0f/128.0f) + EPS);
  kvl16[(size_t)bt * 128 + tid] = __float2bfloat16(v * norm * kw[tid]);
  if (tid < 16) {
    const int j = tid & 7;
    const float c = cosp[t*8 + j], sn = sinp[t*8 + j];
    const float x1 = row[128 + j], x2 = row[136 + j];
    krope16[(size_t)bt * 16 + tid] = __float2bfloat16((tid < 8) ? (x1 * c - x2 * sn)
                                                               : (x2 * c + x1 * sn));
  }
}

// ---- kvb GEMM (K=128, N=1792 permuted) with fused outputs ----
__global__ __launch_bounds__(256, 2)
void gemm_kvb(const __hip_bfloat16* __restrict__ A, const __hip_bfloat16* __restrict__ W,
              __hip_bfloat16* __restrict__ knope, __hip_bfloat16* __restrict__ vt)
{
  __shared__ __hip_bfloat16 As[2][128 * 64];
  __shared__ __hip_bfloat16 Ws[2][64 * 64];
  const int K = 128;
  const int tid = threadIdx.x;
  const int wv = tid >> 6, lane = tid & 63;
  const int m = lane & 15, quad = lane >> 4;
  const int bm = blockIdx.y * 128, bn = blockIdx.x * 64;

  const __hip_bfloat16* ga[4];
  const __hip_bfloat16* gw[2];
  #pragma unroll
  for (int i = 0; i < 4; i++) {
    const int slot = i*256 + tid;
    const int row = slot >> 3, cb = slot & 7;
    ga[i] = A + (size_t)(bm + row) * K + ((cb ^ (row & 7)) << 3);
  }
  #pragma unroll
  for (int i = 0; i < 2; i++) {
    const int slot = i*256 + tid;
    const int row = slot >> 3, cb = slot & 7;
    gw[i] = W + (size_t)(bn + row) * K + ((cb ^ (row & 7)) << 3);
  }
  auto stage = [&](int buf){
    #pragma unroll
    for (int i = 0; i < 4; i++) { gload_lds16(ga[i], &As[buf][(i*256 + wv*64)*8]); ga[i] += 64; }
    #pragma unroll
    for (int i = 0; i < 2; i++) { gload_lds16(gw[i], &Ws[buf][(i*256 + wv*64)*8]); gw[i] += 64; }
  };

  f32x4 acc[2][4];
  #pragma unroll
  for (int mi = 0; mi < 2; mi++)
    #pragma unroll
    for (int nj = 0; nj < 4; nj++) acc[mi][nj] = (f32x4){0.f,0.f,0.f,0.f};

  stage(0);
  for (int it = 0; it < 2; it++) {
    const int cur = it & 1;
    __syncthreads();
    if (it == 0) stage(1);
    #pragma unroll
    for (int ks = 0; ks < 2; ks++) {
      const int cb = ((ks*4 + quad) ^ (m & 7)) << 3;
      bf16x8 af[2], wf[4];
      #pragma unroll
      for (int mi = 0; mi < 2; mi++)
        af[mi] = *(const bf16x8*)(&As[cur][(wv*32 + mi*16 + m) * 64 + cb]);
      #pragma unroll
      for (int nj = 0; nj < 4; nj++)
        wf[nj] = *(const bf16x8*)(&Ws[cur][(nj*16 + m) * 64 + cb]);
      #pragma unroll
      for (int mi = 0; mi < 2; mi++)
        #pragma unroll
        for (int nj = 0; nj < 4; nj++)
          acc[mi][nj] = __builtin_amdgcn_mfma_f32_16x16x32_bf16(af[mi], wf[nj], acc[mi][nj], 0, 0, 0);
    }
  }

  if (bn < 768) {
    #pragma unroll
    for (int mi = 0; mi < 2; mi++)
      #pragma unroll
      for (int nj = 0; nj < 4; nj++) {
        const int col = bn + nj*16 + m;
        #pragma unroll
        for (int r = 0; r < 4; r++) {
          const int row = bm + wv*32 + mi*16 + quad*4 + r;
          knope[(size_t)row * 768 + col] = __float2bfloat16(acc[mi][nj][r]);
        }
      }
  } else {
    __syncthreads();
    short* TL = (short*)&As[0][0];          // [64 d][pitch 136]
    #pragma unroll
    for (int mi = 0; mi < 2; mi++)
      #pragma unroll
      for (int nj = 0; nj < 4; nj++) {
        const int d = nj*16 + m;
        #pragma unroll
        for (int r = 0; r < 4; r++) {
          const int tl = wv*32 + mi*16 + quad*4 + r;
          __hip_bfloat16 hv = __float2bfloat16(acc[mi][nj][r]);
          short sv; __builtin_memcpy(&sv, &hv, 2);
          TL[d*136 + tl] = sv;
        }
      }
    __syncthreads();
    const int h = (bn - 768) >> 6;
    const int b = bm >> 11;
    const int t0 = bm & (T_ - 1);
    #pragma unroll
    for (int i = 0; i < 4; i++) {
      const int unit = i*256 + tid;        // 1024 units of 8 elems
      const int d = unit >> 4, tu = unit & 15;
      *(bf16x8*)(vt + ((size_t)(b*NH + h)*64 + d)*T_ + t0 + tu*8)
          = *(const bf16x8*)(TL + d*136 + tu*8);
    }
  }
}

__device__ __forceinline__ void fa_store(float lrun, f32x4 (&oacc)[4],
    const int b, const int qrow0, const int h, const int m, const int quad,
    __hip_bfloat16* __restrict__ aout)
{
  float lr[4];
  #pragma unroll
  for (int r = 0; r < 4; r++) lr[r] = __shfl(lrun, (quad << 2) | r, 64);
  #pragma unroll
  for (int vs = 0; vs < 4; vs++)
    #pragma unroll
    for (int r = 0; r < 4; r++)
      aout[(size_t)(b*T_ + qrow0 + quad*4 + r) * 1024 + h*64 + vs*16 + m]
          = __float2bfloat16(oacc[vs][r] / lr[r]);
}

// Single-tile MFMA flash attention: one 64-query tile per block (grid 32x32 =
// 1024 blocks), BK=128, single-buffered 32KB LDS -> 4+ blocks/CU resident.
// Inter-block overlap covers the stage->sync serialization (m114).
__global__ __launch_bounds__(256, 4)
void attn_single(const __hip_bfloat16* __restrict__ qb,
                 const __hip_bfloat16* __restrict__ knope,
                 const __hip_bfloat16* __restrict__ krope16,
                 const __hip_bfloat16* __restrict__ vt16,
                 __hip_bfloat16* __restrict__ aout)
{
  __shared__ __hip_bfloat16 SL[16384];   // K [128][64] @0 (16KB); V [64][128] @8192 (16KB)
  const int tid = threadIdx.x;
  const int wv = tid >> 6, lane = tid & 63;
  const int m = lane & 15, quad = lane >> 4;
  const int tile = blockIdx.x;          // 0..31
  const int bh = blockIdx.y;
  const int b = bh >> 4, h = bh & 15;
  const int qbase = tile*64 + wv*16;
  const int nt = (tile + 2) >> 1;       // 128-key tiles needed

  const __hip_bfloat16* qr = qb + ((size_t)bh*T_ + qbase + m)*64 + quad*8;
  const bf16x8 q0 = *(const bf16x8*)qr, q1 = *(const bf16x8*)(qr + 32);

  const __hip_bfloat16* pK[4]; size_t iK[4];
  const __hip_bfloat16* pV[4];
  #pragma unroll
  for (int i = 0; i < 4; i++) {
    const int slot = i*256 + tid;
    const int krow = slot >> 3;
    const int kde = (slot & 7) ^ (krow & 7);
    if (kde < 6) { pK[i] = knope + (size_t)(b*T_ + krow)*768 + h*48 + kde*8; iK[i] = (size_t)128*768; }
    else         { pK[i] = krope16 + (size_t)(b*T_ + krow)*16 + (kde-6)*8;   iK[i] = (size_t)128*16; }
    const int vd = slot >> 4;
    const int vde = (slot & 15) ^ (vd & 7);
    pV[i] = vt16 + ((size_t)bh*64 + vd)*T_ + vde*8;
  }

  f32x4 o[4];
  #pragma unroll
  for (int vs = 0; vs < 4; vs++) o[vs] = (f32x4){0.f,0.f,0.f,0.f};
  float mrun = -3.0e38f, lrun = 0.f;
  const int sw0 = quad ^ (m & 7);
  const int qglob = qbase + m;

  for (int kt = 0; kt < nt; kt++) {
    // ---- stage K (16KB) + V (16KB) ----
    #pragma unroll
    for (int i = 0; i < 4; i++) {
      gload_lds16(pK[i], SL + (i*256 + wv*64)*8);
      gload_lds16(pV[i], SL + 8192 + (i*256 + wv*64)*8);
      pK[i] += iK[i]; pV[i] += 128;
    }
    __syncthreads();

    // ---- QK^T: S^T (128 keys x 16 queries) ----
    f32x4 s[8];
    #pragma unroll
    for (int sub = 0; sub < 8; sub++) {
      const bf16x8 kf0 = *(const bf16x8*)(SL + (sub*16 + m)*64 + sw0*8);
      const bf16x8 kf1 = *(const bf16x8*)(SL + (sub*16 + m)*64 + (sw0^4)*8);
      f32x4 z = (f32x4){0.f,0.f,0.f,0.f};
      z = __builtin_amdgcn_mfma_f32_16x16x32_bf16(kf0, q0, z, 0, 0, 0);
      z = __builtin_amdgcn_mfma_f32_16x16x32_bf16(kf1, q1, z, 0, 0, 0);
      s[sub] = z;
    }

    // ---- online softmax (R8 math, p overwrites s in place) ----
    if (kt == nt - 1) {
      #pragma unroll
      for (int sub = 0; sub < 8; sub++)
        #pragma unroll
        for (int r = 0; r < 4; r++)
          if (kt*128 + sub*16 + quad*4 + r > qglob) s[sub][r] = -1e30f;
    }
    float tm = -3.0e38f;
    #pragma unroll
    for (int sub = 0; sub < 8; sub++)
      #pragma unroll
      for (int r = 0; r < 4; r++) tm = fmaxf(tm, s[sub][r]);
    tm = fmaxf(tm, __shfl_xor(tm, 16, 64));
    tm = fmaxf(tm, __shfl_xor(tm, 32, 64));
    const float mn = fmaxf(mrun, tm);
    const float alpha = __expf(mrun - mn);
    float rs = 0.f;
    #pragma unroll
    for (int sub = 0; sub < 8; sub++)
      #pragma unroll
      for (int r = 0; r < 4; r++) {
        const float e = __expf(s[sub][r] - mn);
        s[sub][r] = e; rs += e;
      }
    rs += __shfl_xor(rs, 16, 64);
    rs += __shfl_xor(rs, 32, 64);
    lrun = lrun * alpha + rs;
    mrun = mn;

    unsigned u[8][2];
    #pragma unroll
    for (int sub = 0; sub < 8; sub++) {
      u[sub][0] = pack_bf16(s[sub][0], s[sub][1]);
      u[sub][1] = pack_bf16(s[sub][2], s[sub][3]);
    }
    // shuffle BOTH sub-words, select with DEST quad after (source-lane quad differs)
    bf16x8 a[4];
    #pragma unroll
    for (int c = 0; c < 4; c++) {
      union { int i[4]; bf16x8 v; } au;
      #pragma unroll
      for (int w4 = 0; w4 < 4; w4++) {
        const int src = (((2*quad + (w4 >> 1)) & 3) << 4) | m;
        const int lo = __shfl((int)u[c*2][w4 & 1], src, 64);
        const int hi = __shfl((int)u[c*2+1][w4 & 1], src, 64);
        au.i[w4] = (quad & 2) ? hi : lo;
      }
      a[c] = au.v;
    }

    float al[4];
    #pragma unroll
    for (int r = 0; r < 4; r++) al[r] = __shfl(alpha, (quad << 2) | r, 64);
    #pragma unroll
    for (int vs = 0; vs < 4; vs++)
      #pragma unroll
      for (int r = 0; r < 4; r++) o[vs][r] *= al[r];

    // ---- O += P V ----
    #pragma unroll
    for (int vs = 0; vs < 4; vs++) {
      #pragma unroll
      for (int c = 0; c < 4; c++) {
        const bf16x8 vf = *(const bf16x8*)(SL + 8192 + (vs*16 + m)*128 + (((c*4 + quad) ^ (m & 7)) << 3));
        o[vs] = __builtin_amdgcn_mfma_f32_16x16x32_bf16(a[c], vf, o[vs], 0, 0, 0);
      }
    }
    if (kt + 1 < nt) __syncthreads();   // protect LDS before next stage
  }

  fa_store(lrun, o, b, qbase, h, m, quad, aout);
}

extern "C" void kernel_launch(void* const* d_in, const int* in_sizes, int n_in,
                              void* d_out, int out_size, void* d_ws, size_t ws_size,
                              hipStream_t stream)
{
  const float* x    = (const float*)d_in[0];
  const float* cosp = (const float*)d_in[1];
  const float* sinp = (const float*)d_in[2];
  const float* Wq   = (const float*)d_in[3];
  const float* qw   = (const float*)d_in[4];
  const float* Wkva = (const float*)d_in[5];
  const float* kw   = (const float*)d_in[6];
  const float* Wkvb = (const float*)d_in[7];
  const float* Wo   = (const float*)d_in[8];
  float* out = (float*)d_out;

  float* kva = (float*)d_ws;                                  //   589,824 f
  __hip_bfloat16* xb16    = (__hip_bfloat16*)(kva + 589824);  // 4,194,304
  __hip_bfloat16* knope16 = xb16 + 4194304;                   // 3,145,728
  __hip_bfloat16* kvl16   = knope16 + 3145728;                //   524,288
  __hip_bfloat16* qb16    = kvl16 + 524288;                   // 4,194,304
  __hip_bfloat16* vt16    = qb16 + 4194304;                   // 4,194,304
  __hip_bfloat16* krope16 = vt16 + 4194304;                   //    65,536
  __hip_bfloat16* Wqb     = krope16 + 65536;                  // 1,048,576
  __hip_bfloat16* Wkvab   = Wqb + 1048576;                    //   147,456
  __hip_bfloat16* Wkvbb   = Wkvab + 147456;                   //   229,376
  __hip_bfloat16* Wob     = Wkvbb + 229376;                   // 1,048,576
  __hip_bfloat16* ab16    = Wob + 1048576;                    // 4,194,304

  const int M = B_ * T_;   // 4096

  cvt5<<<6512, 256, 0, stream>>>(x, Wq, Wkva, Wkvb, Wo, xb16, Wqb, Wkvab, Wkvbb, Wob);
  gemm_qkva<<<dim3(19, 32), 256, 0, stream>>>(xb16, Wqb, Wkvab, qw, cosp, sinp, qb16, kva);
  prep_kv<<<M, 128, 0, stream>>>(kva, kw, cosp, sinp, kvl16, krope16);
  gemm_kvb<<<dim3(28, 32), 256, 0, stream>>>(kvl16, Wkvbb, knope16, vt16);
  attn_single<<<dim3(32, B_ * NH), 256, 0, stream>>>(qb16, knope16, krope16, vt16, ab16);
  gemm_bt64<float><<<dim3(16, 32), 256, 0, stream>>>(ab16, Wob, out, M, 1024, 1024);
}

// Round 11
// 187.695 us; speedup vs baseline: 1.1397x; 1.1397x over previous
//
#include <hip/hip_runtime.h>
#include <hip/hip_bf16.h>
#include <math.h>

#define NH 16
#define T_ 2048
#define B_ 2
#define D_ 1024
#define EPS 1e-6f

typedef __attribute__((ext_vector_type(8))) short bf16x8;
typedef __attribute__((ext_vector_type(4))) float f32x4;

__device__ __forceinline__ float wred_sum(float v){
  #pragma unroll
  for (int o = 32; o > 0; o >>= 1) v += __shfl_xor(v, o, 64);
  return v;
}

__device__ __forceinline__ unsigned pack_bf16(float a, float b){
  __hip_bfloat162 t = __float22bfloat162_rn(make_float2(a, b));
  unsigned r; __builtin_memcpy(&r, &t, 4); return r;
}

__device__ __forceinline__ void gload_lds16(const void* g, void* l){
  __builtin_amdgcn_global_load_lds((const __attribute__((address_space(1))) void*)g,
                                   (__attribute__((address_space(3))) void*)l, 16, 0, 0);
}

// ---- convert x + weights to bf16; Wkvb rows PERMUTED: [h*48+d | 768+h*64+dv] ----
__global__ __launch_bounds__(256)
void cvt5(const float* __restrict__ x, const float* __restrict__ wq,
          const float* __restrict__ wkva, const float* __restrict__ wkvb,
          const float* __restrict__ wo,
          __hip_bfloat16* __restrict__ xb, __hip_bfloat16* __restrict__ wqb,
          __hip_bfloat16* __restrict__ wkvab, __hip_bfloat16* __restrict__ wkvbb,
          __hip_bfloat16* __restrict__ wob)
{
  const int i = blockIdx.x * 256 + threadIdx.x;     // float4 index, 1,667,072 total
  const float* s; __hip_bfloat16* d; size_t soff, doff;
  if      (i < 1048576) { s = x;    d = xb;    soff = doff = i; }
  else if (i < 1310720) { s = wq;   d = wqb;   soff = doff = i - 1048576; }
  else if (i < 1347584) { s = wkva; d = wkvab; soff = doff = i - 1310720; }
  else if (i < 1404928) {
    const int off = i - 1347584;                    // float4 idx into 1792x128
    const int srow = off >> 5, c4 = off & 31;
    const int h = srow / 112, dd = srow % 112;
    const int drow = (dd < 48) ? (h*48 + dd) : (768 + h*64 + (dd - 48));
    s = wkvb; d = wkvbb; soff = off; doff = (size_t)drow*32 + c4;
  }
  else                  { s = wo;   d = wob;   soff = doff = i - 1404928; }
  float4 v = *(const float4*)(s + soff * 4);
  *(__hip_bfloat162*)(d + doff * 4)     = __float22bfloat162_rn(make_float2(v.x, v.y));
  *(__hip_bfloat162*)(d + doff * 4 + 2) = __float22bfloat162_rn(make_float2(v.z, v.w));
}

// ---- bf16 MFMA GEMM, 128x64 tile, DOUBLE-BUFFERED staging (48KB LDS) ----
template<typename CT>
__global__ __launch_bounds__(256, 2)
void gemm_bt64(const __hip_bfloat16* __restrict__ A, const __hip_bfloat16* __restrict__ W,
               CT* __restrict__ C, int M, int N, int K)
{
  __shared__ __hip_bfloat16 As[2][128 * 64];   // 32 KB
  __shared__ __hip_bfloat16 Ws[2][64 * 64];    // 16 KB
  const int tid = threadIdx.x;
  const int wv = tid >> 6, lane = tid & 63;
  const int m = lane & 15, quad = lane >> 4;
  const int bm = blockIdx.y * 128, bn = blockIdx.x * 64;

  const __hip_bfloat16* ga[4];
  const __hip_bfloat16* gw[2];
  #pragma unroll
  for (int i = 0; i < 4; i++) {
    const int slot = i*256 + tid;
    const int row = slot >> 3, cb = slot & 7;
    ga[i] = A + (size_t)(bm + row) * K + ((cb ^ (row & 7)) << 3);
  }
  #pragma unroll
  for (int i = 0; i < 2; i++) {
    const int slot = i*256 + tid;
    const int row = slot >> 3, cb = slot & 7;
    int wr = bn + row; if (wr >= N) wr = N - 1;
    gw[i] = W + (size_t)wr * K + ((cb ^ (row & 7)) << 3);
  }
  auto stage = [&](int buf){
    #pragma unroll
    for (int i = 0; i < 4; i++) { gload_lds16(ga[i], &As[buf][(i*256 + wv*64)*8]); ga[i] += 64; }
    #pragma unroll
    for (int i = 0; i < 2; i++) { gload_lds16(gw[i], &Ws[buf][(i*256 + wv*64)*8]); gw[i] += 64; }
  };

  f32x4 acc[2][4];
  #pragma unroll
  for (int mi = 0; mi < 2; mi++)
    #pragma unroll
    for (int nj = 0; nj < 4; nj++) acc[mi][nj] = (f32x4){0.f,0.f,0.f,0.f};

  stage(0);
  const int iters = K >> 6;
  for (int it = 0; it < iters; it++) {
    const int cur = it & 1;
    __syncthreads();
    if (it + 1 < iters) stage(cur ^ 1);
    #pragma unroll
    for (int ks = 0; ks < 2; ks++) {
      const int cb = ((ks*4 + quad) ^ (m & 7)) << 3;
      bf16x8 af[2], wf[4];
      #pragma unroll
      for (int mi = 0; mi < 2; mi++)
        af[mi] = *(const bf16x8*)(&As[cur][(wv*32 + mi*16 + m) * 64 + cb]);
      #pragma unroll
      for (int nj = 0; nj < 4; nj++)
        wf[nj] = *(const bf16x8*)(&Ws[cur][(nj*16 + m) * 64 + cb]);
      #pragma unroll
      for (int mi = 0; mi < 2; mi++)
        #pragma unroll
        for (int nj = 0; nj < 4; nj++)
          acc[mi][nj] = __builtin_amdgcn_mfma_f32_16x16x32_bf16(af[mi], wf[nj], acc[mi][nj], 0, 0, 0);
    }
  }

  #pragma unroll
  for (int mi = 0; mi < 2; mi++)
    #pragma unroll
    for (int nj = 0; nj < 4; nj++) {
      const int col = bn + nj*16 + m;
      if (col < N) {
        #pragma unroll
        for (int r = 0; r < 4; r++) {
          const int row = bm + wv*32 + mi*16 + quad*4 + r;
          if constexpr (sizeof(CT) == 2)
            C[(size_t)row * N + col] = (CT)__float2bfloat16(acc[mi][nj][r]);
          else
            C[(size_t)row * N + col] = acc[mi][nj][r];
        }
      }
    }
}

// ---- merged Wq(+fused RMSNorm/RoPE) and Wkva GEMM: one launch, K=1024 ----
// q prescale now folds log2(e): attention softmax runs in exp2 domain.
__global__ __launch_bounds__(256, 2)
void gemm_qkva(const __hip_bfloat16* __restrict__ A, const __hip_bfloat16* __restrict__ Wqb,
               const __hip_bfloat16* __restrict__ Wkvab,
               const float* __restrict__ qw, const float* __restrict__ cosp,
               const float* __restrict__ sinp,
               __hip_bfloat16* __restrict__ qb, float* __restrict__ kva)
{
  __shared__ __hip_bfloat16 As[2][128 * 64];
  __shared__ __hip_bfloat16 Ws[2][64 * 64];
  const int K = 1024;
  const int tid = threadIdx.x;
  const int wv = tid >> 6, lane = tid & 63;
  const int m = lane & 15, quad = lane >> 4;
  const int bm = blockIdx.y * 128;
  const bool isq = blockIdx.x < 16;
  const __hip_bfloat16* W = isq ? Wqb : Wkvab;
  const int bn = isq ? blockIdx.x*64 : (blockIdx.x - 16)*64;
  const int Nw = isq ? 1024 : 144;

  const __hip_bfloat16* ga[4];
  const __hip_bfloat16* gw[2];
  #pragma unroll
  for (int i = 0; i < 4; i++) {
    const int slot = i*256 + tid;
    const int row = slot >> 3, cb = slot & 7;
    ga[i] = A + (size_t)(bm + row) * K + ((cb ^ (row & 7)) << 3);
  }
  #pragma unroll
  for (int i = 0; i < 2; i++) {
    const int slot = i*256 + tid;
    const int row = slot >> 3, cb = slot & 7;
    int wr = bn + row; if (wr >= Nw) wr = Nw - 1;
    gw[i] = W + (size_t)wr * K + ((cb ^ (row & 7)) << 3);
  }
  auto stage = [&](int buf){
    #pragma unroll
    for (int i = 0; i < 4; i++) { gload_lds16(ga[i], &As[buf][(i*256 + wv*64)*8]); ga[i] += 64; }
    #pragma unroll
    for (int i = 0; i < 2; i++) { gload_lds16(gw[i], &Ws[buf][(i*256 + wv*64)*8]); gw[i] += 64; }
  };

  f32x4 acc[2][4];
  #pragma unroll
  for (int mi = 0; mi < 2; mi++)
    #pragma unroll
    for (int nj = 0; nj < 4; nj++) acc[mi][nj] = (f32x4){0.f,0.f,0.f,0.f};

  stage(0);
  for (int it = 0; it < 16; it++) {
    const int cur = it & 1;
    __syncthreads();
    if (it < 15) stage(cur ^ 1);
    #pragma unroll
    for (int ks = 0; ks < 2; ks++) {
      const int cb = ((ks*4 + quad) ^ (m & 7)) << 3;
      bf16x8 af[2], wf[4];
      #pragma unroll
      for (int mi = 0; mi < 2; mi++)
        af[mi] = *(const bf16x8*)(&As[cur][(wv*32 + mi*16 + m) * 64 + cb]);
      #pragma unroll
      for (int nj = 0; nj < 4; nj++)
        wf[nj] = *(const bf16x8*)(&Ws[cur][(nj*16 + m) * 64 + cb]);
      #pragma unroll
      for (int mi = 0; mi < 2; mi++)
        #pragma unroll
        for (int nj = 0; nj < 4; nj++)
          acc[mi][nj] = __builtin_amdgcn_mfma_f32_16x16x32_bf16(af[mi], wf[nj], acc[mi][nj], 0, 0, 0);
    }
  }

  if (isq) {
    const int head = blockIdx.x;
    float qwv[4];
    #pragma unroll
    for (int nj = 0; nj < 4; nj++) qwv[nj] = qw[nj*16 + m];
    const int j = m & 7;
    const float qscale = 0.125f * 1.44269504f;
    #pragma unroll
    for (int mi = 0; mi < 2; mi++) {
      #pragma unroll
      for (int r = 0; r < 4; r++) {
        float ss = 0.f;
        #pragma unroll
        for (int nj = 0; nj < 4; nj++) { const float t = acc[mi][nj][r]; ss = fmaf(t, t, ss); }
        ss += __shfl_xor(ss, 1, 64); ss += __shfl_xor(ss, 2, 64);
        ss += __shfl_xor(ss, 4, 64); ss += __shfl_xor(ss, 8, 64);
        const float nrm = rsqrtf(ss * (1.0f/64.0f) + EPS);
        float v[4];
        #pragma unroll
        for (int nj = 0; nj < 4; nj++) v[nj] = acc[mi][nj][r] * nrm * qwv[nj];
        const int grow = bm + wv*32 + mi*16 + quad*4 + r;
        const int t = grow & (T_ - 1);
        const int b = grow >> 11;
        const float part = __shfl_xor(v[3], 8, 64);
        const float c = cosp[t*8 + j], sn = sinp[t*8 + j];
        v[3] = (m < 8) ? (v[3]*c - part*sn) : (v[3]*c + part*sn);
        __hip_bfloat16* dst = qb + ((size_t)(b*NH + head)*T_ + t)*64 + m;
        #pragma unroll
        for (int nj = 0; nj < 4; nj++) dst[nj*16] = __float2bfloat16(v[nj] * qscale);
      }
    }
  } else {
    #pragma unroll
    for (int mi = 0; mi < 2; mi++)
      #pragma unroll
      for (int nj = 0; nj < 4; nj++) {
        const int col = bn + nj*16 + m;
        if (col < 144) {
          #pragma unroll
          for (int r = 0; r < 4; r++) {
            const int row = bm + wv*32 + mi*16 + quad*4 + r;
            kva[(size_t)row * 144 + col] = acc[mi][nj][r];
          }
        }
      }
  }
}

// Per (b,t): RMSNorm over kv_a[:128] -> kvl16; RoPE on kv_a[128:144] -> krope16.
__global__ void prep_kv(const float* __restrict__ kva, const float* __restrict__ kw,
                        const float* __restrict__ cosp, const float* __restrict__ sinp,
                        __hip_bfloat16* __restrict__ kvl16, __hip_bfloat16* __restrict__ krope16)
{
  const int tid = threadIdx.x;   // 0..127
  const int bt = blockIdx.x;
  const int t = bt % T_;
  const float* row = kva + (size_t)bt * 144;
  const float v = row[tid];
  float s = wred_sum(v * v);
  __shared__ float red[2];
  if ((tid & 63) == 0) red[tid >> 6] = s;
  __syncthreads();
  const float total = red[0] + red[1];
  const float norm = rsqrtf(total * (1.0f/128.0f) + EPS);
  kvl16[(size_t)bt * 128 + tid] = __float2bfloat16(v * norm * kw[tid]);
  if (tid < 16) {
    const int j = tid & 7;
    const float c = cosp[t*8 + j], sn = sinp[t*8 + j];
    const float x1 = row[128 + j], x2 = row[136 + j];
    krope16[(size_t)bt * 16 + tid] = __float2bfloat16((tid < 8) ? (x1 * c - x2 * sn)
                                                               : (x2 * c + x1 * sn));
  }
}

// ---- kvb GEMM (K=128, N=1792 permuted) with fused outputs ----
__global__ __launch_bounds__(256, 2)
void gemm_kvb(const __hip_bfloat16* __restrict__ A, const __hip_bfloat16* __restrict__ W,
              __hip_bfloat16* __restrict__ knope, __hip_bfloat16* __restrict__ vt)
{
  __shared__ __hip_bfloat16 As[2][128 * 64];
  __shared__ __hip_bfloat16 Ws[2][64 * 64];
  const int K = 128;
  const int tid = threadIdx.x;
  const int wv = tid >> 6, lane = tid & 63;
  const int m = lane & 15, quad = lane >> 4;
  const int bm = blockIdx.y * 128, bn = blockIdx.x * 64;

  const __hip_bfloat16* ga[4];
  const __hip_bfloat16* gw[2];
  #pragma unroll
  for (int i = 0; i < 4; i++) {
    const int slot = i*256 + tid;
    const int row = slot >> 3, cb = slot & 7;
    ga[i] = A + (size_t)(bm + row) * K + ((cb ^ (row & 7)) << 3);
  }
  #pragma unroll
  for (int i = 0; i < 2; i++) {
    const int slot = i*256 + tid;
    const int row = slot >> 3, cb = slot & 7;
    gw[i] = W + (size_t)(bn + row) * K + ((cb ^ (row & 7)) << 3);
  }
  auto stage = [&](int buf){
    #pragma unroll
    for (int i = 0; i < 4; i++) { gload_lds16(ga[i], &As[buf][(i*256 + wv*64)*8]); ga[i] += 64; }
    #pragma unroll
    for (int i = 0; i < 2; i++) { gload_lds16(gw[i], &Ws[buf][(i*256 + wv*64)*8]); gw[i] += 64; }
  };

  f32x4 acc[2][4];
  #pragma unroll
  for (int mi = 0; mi < 2; mi++)
    #pragma unroll
    for (int nj = 0; nj < 4; nj++) acc[mi][nj] = (f32x4){0.f,0.f,0.f,0.f};

  stage(0);
  for (int it = 0; it < 2; it++) {
    const int cur = it & 1;
    __syncthreads();
    if (it == 0) stage(1);
    #pragma unroll
    for (int ks = 0; ks < 2; ks++) {
      const int cb = ((ks*4 + quad) ^ (m & 7)) << 3;
      bf16x8 af[2], wf[4];
      #pragma unroll
      for (int mi = 0; mi < 2; mi++)
        af[mi] = *(const bf16x8*)(&As[cur][(wv*32 + mi*16 + m) * 64 + cb]);
      #pragma unroll
      for (int nj = 0; nj < 4; nj++)
        wf[nj] = *(const bf16x8*)(&Ws[cur][(nj*16 + m) * 64 + cb]);
      #pragma unroll
      for (int mi = 0; mi < 2; mi++)
        #pragma unroll
        for (int nj = 0; nj < 4; nj++)
          acc[mi][nj] = __builtin_amdgcn_mfma_f32_16x16x32_bf16(af[mi], wf[nj], acc[mi][nj], 0, 0, 0);
    }
  }

  if (bn < 768) {
    #pragma unroll
    for (int mi = 0; mi < 2; mi++)
      #pragma unroll
      for (int nj = 0; nj < 4; nj++) {
        const int col = bn + nj*16 + m;
        #pragma unroll
        for (int r = 0; r < 4; r++) {
          const int row = bm + wv*32 + mi*16 + quad*4 + r;
          knope[(size_t)row * 768 + col] = __float2bfloat16(acc[mi][nj][r]);
        }
      }
  } else {
    __syncthreads();
    short* TL = (short*)&As[0][0];          // [64 d][pitch 136]
    #pragma unroll
    for (int mi = 0; mi < 2; mi++)
      #pragma unroll
      for (int nj = 0; nj < 4; nj++) {
        const int d = nj*16 + m;
        #pragma unroll
        for (int r = 0; r < 4; r++) {
          const int tl = wv*32 + mi*16 + quad*4 + r;
          __hip_bfloat16 hv = __float2bfloat16(acc[mi][nj][r]);
          short sv; __builtin_memcpy(&sv, &hv, 2);
          TL[d*136 + tl] = sv;
        }
      }
    __syncthreads();
    const int h = (bn - 768) >> 6;
    const int b = bm >> 11;
    const int t0 = bm & (T_ - 1);
    #pragma unroll
    for (int i = 0; i < 4; i++) {
      const int unit = i*256 + tid;        // 1024 units of 8 elems
      const int d = unit >> 4, tu = unit & 15;
      *(bf16x8*)(vt + ((size_t)(b*NH + h)*64 + d)*T_ + t0 + tu*8)
          = *(const bf16x8*)(TL + d*136 + tu*8);
    }
  }
}

// ---- fixed-shift softmax update (exp2 domain, shift 48): no running max, no
// alpha/rescale; l accumulates per-lane, reduced once in the epilogue. ----
__device__ __forceinline__ void fa_softmax_fixed(f32x4 (&s)[8], const bool diag,
    const int k0, const int qglob, const int m, const int quad,
    float& lrun, bf16x8 (&a)[4])
{
  if (diag) {
    #pragma unroll
    for (int sub = 0; sub < 8; sub++)
      #pragma unroll
      for (int r = 0; r < 4; r++)
        if (k0 + sub*16 + quad*4 + r > qglob) s[sub][r] = -1e30f;
  }
  float p[8][4];
  #pragma unroll
  for (int sub = 0; sub < 8; sub++)
    #pragma unroll
    for (int r = 0; r < 4; r++) {
      const float e = exp2f(s[sub][r] - 48.0f);
      p[sub][r] = e; lrun += e;
    }

  unsigned u[8][2];
  #pragma unroll
  for (int sub = 0; sub < 8; sub++) {
    u[sub][0] = pack_bf16(p[sub][0], p[sub][1]);
    u[sub][1] = pack_bf16(p[sub][2], p[sub][3]);
  }
  // shuffle BOTH sub-words, select with DEST quad after (source-lane quad differs)
  #pragma unroll
  for (int c = 0; c < 4; c++) {
    union { int i[4]; bf16x8 v; } au;
    #pragma unroll
    for (int w4 = 0; w4 < 4; w4++) {
      const int src = (((2*quad + (w4 >> 1)) & 3) << 4) | m;
      const int lo = __shfl((int)u[c*2][w4 & 1], src, 64);
      const int hi = __shfl((int)u[c*2+1][w4 & 1], src, 64);
      au.i[w4] = (quad & 2) ? hi : lo;
    }
    a[c] = au.v;
  }
}

__device__ __forceinline__ void fa_store(float lrun, f32x4 (&oacc)[4],
    const int b, const int qrow0, const int h, const int m, const int quad,
    __hip_bfloat16* __restrict__ aout)
{
  // finish the l reduction (partial per lane over this lane's keys for query m)
  lrun += __shfl_xor(lrun, 16, 64);
  lrun += __shfl_xor(lrun, 32, 64);
  float lr[4];
  #pragma unroll
  for (int r = 0; r < 4; r++) lr[r] = __shfl(lrun, (quad << 2) | r, 64);
  #pragma unroll
  for (int vs = 0; vs < 4; vs++)
    #pragma unroll
    for (int r = 0; r < 4; r++)
      aout[(size_t)(b*T_ + qrow0 + quad*4 + r) * 1024 + h*64 + vs*16 + m]
          = __float2bfloat16(oacc[vs][r] / lr[r]);
}

// Pair-balanced MFMA flash attention, BK=128, dbuf staging, fixed-shift softmax.
__global__ __launch_bounds__(256, 2)
void attn_pair2(const __hip_bfloat16* __restrict__ qb,
                const __hip_bfloat16* __restrict__ knope,
                const __hip_bfloat16* __restrict__ krope16,
                const __hip_bfloat16* __restrict__ vt16,
                __hip_bfloat16* __restrict__ aout)
{
  __shared__ __hip_bfloat16 SL[32768];   // K: [buf][128][64] @0/8192; V: [buf][64][128] @16384/24576
  const int tid = threadIdx.x;
  const int wv = tid >> 6, lane = tid & 63;
  const int m = lane & 15, quad = lane >> 4;
  const int ta = blockIdx.x;            // 0..15
  const int tb = 31 - ta;               // 16..31
  const int bh = blockIdx.y;
  const int b = bh >> 4, h = bh & 15;
  const int qbaseA = ta*64 + wv*16;
  const int qbaseB = tb*64 + wv*16;
  const int ntA = (ta + 2) >> 1;
  const int ntB = (tb + 2) >> 1;

  const __hip_bfloat16* qra = qb + ((size_t)bh*T_ + qbaseA + m)*64 + quad*8;
  const bf16x8 qA0 = *(const bf16x8*)qra, qA1 = *(const bf16x8*)(qra + 32);
  const __hip_bfloat16* qrb = qb + ((size_t)bh*T_ + qbaseB + m)*64 + quad*8;
  const bf16x8 qB0 = *(const bf16x8*)qrb, qB1 = *(const bf16x8*)(qrb + 32);

  const __hip_bfloat16* pK[4]; size_t iK[4];
  const __hip_bfloat16* pV[4];
  #pragma unroll
  for (int i = 0; i < 4; i++) {
    const int slot = i*256 + tid;
    const int krow = slot >> 3;
    const int kde = (slot & 7) ^ (krow & 7);
    if (kde < 6) { pK[i] = knope + (size_t)(b*T_ + krow)*768 + h*48 + kde*8; iK[i] = (size_t)128*768; }
    else         { pK[i] = krope16 + (size_t)(b*T_ + krow)*16 + (kde-6)*8;   iK[i] = (size_t)128*16; }
    const int vd = slot >> 4;
    const int vde = (slot & 15) ^ (vd & 7);
    pV[i] = vt16 + ((size_t)bh*64 + vd)*T_ + vde*8;
  }

  auto stage = [&](int buf){
    #pragma unroll
    for (int i = 0; i < 4; i++) {
      gload_lds16(pK[i], SL + buf*8192 + (i*256 + wv*64)*8);
      gload_lds16(pV[i], SL + 16384 + buf*8192 + (i*256 + wv*64)*8);
      pK[i] += iK[i]; pV[i] += 128;
    }
  };

  f32x4 oA[4], oB[4];
  #pragma unroll
  for (int vs = 0; vs < 4; vs++) { oA[vs] = (f32x4){0.f,0.f,0.f,0.f}; oB[vs] = (f32x4){0.f,0.f,0.f,0.f}; }
  float lA = 0.f, lB = 0.f;

  const int sw0 = quad ^ (m & 7);
  stage(0);

  for (int kt = 0; kt < ntB; kt++) {
    const int cur = kt & 1;
    __syncthreads();
    const __hip_bfloat16* Kc = SL + cur*8192;
    const __hip_bfloat16* Vc = SL + 16384 + cur*8192;
    const bool doA = (kt < ntA);

    f32x4 sA[8], sB[8];
    #pragma unroll
    for (int sub = 0; sub < 8; sub++) {
      const bf16x8 kf0 = *(const bf16x8*)(Kc + (sub*16 + m)*64 + sw0*8);
      const bf16x8 kf1 = *(const bf16x8*)(Kc + (sub*16 + m)*64 + (sw0^4)*8);
      f32x4 z = (f32x4){0.f,0.f,0.f,0.f};
      z = __builtin_amdgcn_mfma_f32_16x16x32_bf16(kf0, qB0, z, 0, 0, 0);
      z = __builtin_amdgcn_mfma_f32_16x16x32_bf16(kf1, qB1, z, 0, 0, 0);
      sB[sub] = z;
      if (doA) {
        f32x4 y = (f32x4){0.f,0.f,0.f,0.f};
        y = __builtin_amdgcn_mfma_f32_16x16x32_bf16(kf0, qA0, y, 0, 0, 0);
        y = __builtin_amdgcn_mfma_f32_16x16x32_bf16(kf1, qA1, y, 0, 0, 0);
        sA[sub] = y;
      }
    }

    if (kt + 1 < ntB) stage(cur ^ 1);

    bf16x8 aA[4], aB[4];
    fa_softmax_fixed(sB, kt == ntB-1, kt*128, qbaseB + m, m, quad, lB, aB);
    if (doA) fa_softmax_fixed(sA, kt == ntA-1, kt*128, qbaseA + m, m, quad, lA, aA);

    #pragma unroll
    for (int vs = 0; vs < 4; vs++) {
      #pragma unroll
      for (int c = 0; c < 4; c++) {
        const bf16x8 vf = *(const bf16x8*)(Vc + (vs*16 + m)*128 + (((c*4 + quad) ^ (m & 7)) << 3));
        oB[vs] = __builtin_amdgcn_mfma_f32_16x16x32_bf16(aB[c], vf, oB[vs], 0, 0, 0);
        if (doA) oA[vs] = __builtin_amdgcn_mfma_f32_16x16x32_bf16(aA[c], vf, oA[vs], 0, 0, 0);
      }
    }
  }

  fa_store(lA, oA, b, qbaseA, h, m, quad, aout);
  fa_store(lB, oB, b, qbaseB, h, m, quad, aout);
}

extern "C" void kernel_launch(void* const* d_in, const int* in_sizes, int n_in,
                              void* d_out, int out_size, void* d_ws, size_t ws_size,
                              hipStream_t stream)
{
  const float* x    = (const float*)d_in[0];
  const float* cosp = (const float*)d_in[1];
  const float* sinp = (const float*)d_in[2];
  const float* Wq   = (const float*)d_in[3];
  const float* qw   = (const float*)d_in[4];
  const float* Wkva = (const float*)d_in[5];
  const float* kw   = (const float*)d_in[6];
  const float* Wkvb = (const float*)d_in[7];
  const float* Wo   = (const float*)d_in[8];
  float* out = (float*)d_out;

  float* kva = (float*)d_ws;                                  //   589,824 f
  __hip_bfloat16* xb16    = (__hip_bfloat16*)(kva + 589824);  // 4,194,304
  __hip_bfloat16* knope16 = xb16 + 4194304;                   // 3,145,728
  __hip_bfloat16* kvl16   = knope16 + 3145728;                //   524,288
  __hip_bfloat16* qb16    = kvl16 + 524288;                   // 4,194,304
  __hip_bfloat16* vt16    = qb16 + 4194304;                   // 4,194,304
  __hip_bfloat16* krope16 = vt16 + 4194304;                   //    65,536
  __hip_bfloat16* Wqb     = krope16 + 65536;                  // 1,048,576
  __hip_bfloat16* Wkvab   = Wqb + 1048576;                    //   147,456
  __hip_bfloat16* Wkvbb   = Wkvab + 147456;                   //   229,376
  __hip_bfloat16* Wob     = Wkvbb + 229376;                   // 1,048,576
  __hip_bfloat16* ab16    = Wob + 1048576;                    // 4,194,304

  const int M = B_ * T_;   // 4096

  cvt5<<<6512, 256, 0, stream>>>(x, Wq, Wkva, Wkvb, Wo, xb16, Wqb, Wkvab, Wkvbb, Wob);
  gemm_qkva<<<dim3(19, 32), 256, 0, stream>>>(xb16, Wqb, Wkvab, qw, cosp, sinp, qb16, kva);
  prep_kv<<<M, 128, 0, stream>>>(kva, kw, cosp, sinp, kvl16, krope16);
  gemm_kvb<<<dim3(28, 32), 256, 0, stream>>>(kvl16, Wkvbb, knope16, vt16);
  attn_pair2<<<dim3(16, B_ * NH), 256, 0, stream>>>(qb16, knope16, krope16, vt16, ab16);
  gemm_bt64<float><<<dim3(16, 32), 256, 0, stream>>>(ab16, Wob, out, M, 1024, 1024);
}